// Round 1
// baseline (1320.447 us; speedup 1.0000x reference)
//
#include <hip/hip_runtime.h>
#include <math.h>

#define NN 100000
#define NE 3200000
#define FIN 512
#define NH 8
#define C1 8
#define HC1 64
#define C2 10
#define HC2 80
#define SCAN_NB 98   // ceil(NN/1024)

// ---------------- static scratch (compile-time sizes; ~104MB) ----------------
__device__ float g_h1[NN * HC1];     // x @ W1
__device__ float g_hact[NN * HC1];   // elu(agg1 + b1)
__device__ float g_h2[NN * HC2];     // hact @ W2
__device__ float g_ssrc[NN * NH];
__device__ float g_sdst[NN * NH];
__device__ int   g_deg[NN];
__device__ int   g_cursor[NN];
__device__ int   g_off[NN + 1];
__device__ int   g_bsum[128];
__device__ int   g_csr[NE];

__device__ __forceinline__ float lrelu(float x) { return x > 0.f ? x : 0.2f * x; }

// ---------------- CSR build ----------------
__global__ __launch_bounds__(256) void zero_kernel() {
  int i = blockIdx.x * 256 + threadIdx.x;
  if (i < NN) { g_deg[i] = 0; g_cursor[i] = 0; }
}

__global__ __launch_bounds__(256) void hist_kernel(const int* __restrict__ ei) {
  int e = blockIdx.x * 256 + threadIdx.x;
  if (e < NE) atomicAdd(&g_deg[ei[NE + e]], 1);
}

__global__ __launch_bounds__(256) void scan_block_kernel() {
  __shared__ int sd[256];
  int tid = threadIdx.x;
  int base = blockIdx.x * 1024 + tid * 4;
  int v0 = (base + 0 < NN) ? g_deg[base + 0] : 0;
  int v1 = (base + 1 < NN) ? g_deg[base + 1] : 0;
  int v2 = (base + 2 < NN) ? g_deg[base + 2] : 0;
  int v3 = (base + 3 < NN) ? g_deg[base + 3] : 0;
  int t1 = v0 + v1, t2 = t1 + v2, t3 = t2 + v3;
  sd[tid] = t3;
  __syncthreads();
  for (int off = 1; off < 256; off <<= 1) {
    int x = (tid >= off) ? sd[tid - off] : 0;
    __syncthreads();
    sd[tid] += x;
    __syncthreads();
  }
  int excl = sd[tid] - t3;
  if (base + 0 < NN) g_off[base + 1] = excl + v0;
  if (base + 1 < NN) g_off[base + 2] = excl + t1;
  if (base + 2 < NN) g_off[base + 3] = excl + t2;
  if (base + 3 < NN) g_off[base + 4] = excl + t3;
  if (tid == 255) g_bsum[blockIdx.x] = sd[255];
}

__global__ void scan_tops_kernel() {  // 1 block, 128 threads
  __shared__ int sd[128];
  int tid = threadIdx.x;
  int v = (tid < SCAN_NB) ? g_bsum[tid] : 0;
  sd[tid] = v;
  __syncthreads();
  for (int off = 1; off < 128; off <<= 1) {
    int x = (tid >= off) ? sd[tid - off] : 0;
    __syncthreads();
    sd[tid] += x;
    __syncthreads();
  }
  g_bsum[tid] = sd[tid] - v;  // exclusive scan of block sums
  if (tid == 0) g_off[0] = 0;
}

__global__ __launch_bounds__(256) void scan_add_kernel() {
  int i = blockIdx.x * 256 + threadIdx.x;
  if (i < NN) g_off[i + 1] += g_bsum[i >> 10];
}

__global__ __launch_bounds__(256) void scatter_kernel(const int* __restrict__ ei) {
  int e = blockIdx.x * 256 + threadIdx.x;
  if (e < NE) {
    int s = ei[e], d = ei[NE + e];
    int pos = g_off[d] + atomicAdd(&g_cursor[d], 1);
    g_csr[pos] = s;
  }
}

// ---------------- GEMM1: g_h1 = X[NN,512] @ W1[512,64] (fp32 tiled) ----------------
__global__ __launch_bounds__(256) void gemm1_kernel(const float* __restrict__ X,
                                                    const float* __restrict__ W) {
  __shared__ float sA[64][64];  // [m][k]
  __shared__ float sB[64][64];  // [k][n]
  int tid = threadIdx.x;
  int r0 = blockIdx.x * 64;
  int tx = tid & 15, ty = tid >> 4;
  int lrow = tid >> 4;   // 0..15
  int lc4 = tid & 15;    // float4 index
  float acc[4][4] = {{0.f, 0.f, 0.f, 0.f}};
  for (int k0 = 0; k0 < FIN; k0 += 64) {
#pragma unroll
    for (int rr = 0; rr < 4; rr++) {
      int m = lrow + rr * 16;
      int row = r0 + m; if (row >= NN) row = NN - 1;
      float4 v = *(const float4*)&X[row * FIN + k0 + lc4 * 4];
      *(float4*)&sA[m][lc4 * 4] = v;
      float4 w = *(const float4*)&W[(k0 + m) * HC1 + lc4 * 4];
      *(float4*)&sB[m][lc4 * 4] = w;
    }
    __syncthreads();
#pragma unroll
    for (int kk = 0; kk < 64; kk += 4) {
      float4 a4[4];
#pragma unroll
      for (int i = 0; i < 4; i++) a4[i] = *(const float4*)&sA[ty * 4 + i][kk];
#pragma unroll
      for (int c = 0; c < 4; c++) {
        float4 b = *(const float4*)&sB[kk + c][tx * 4];
#pragma unroll
        for (int i = 0; i < 4; i++) {
          float a = (c == 0) ? a4[i].x : (c == 1) ? a4[i].y : (c == 2) ? a4[i].z : a4[i].w;
          acc[i][0] = fmaf(a, b.x, acc[i][0]);
          acc[i][1] = fmaf(a, b.y, acc[i][1]);
          acc[i][2] = fmaf(a, b.z, acc[i][2]);
          acc[i][3] = fmaf(a, b.w, acc[i][3]);
        }
      }
    }
    __syncthreads();
  }
#pragma unroll
  for (int i = 0; i < 4; i++) {
    int row = r0 + ty * 4 + i;
    if (row < NN) {
      float4 v = make_float4(acc[i][0], acc[i][1], acc[i][2], acc[i][3]);
      *(float4*)&g_h1[row * HC1 + tx * 4] = v;
    }
  }
}

// ---------------- attention scores s_src/s_dst ----------------
template <int LAYER>
__global__ __launch_bounds__(256) void s_kernel(const float* __restrict__ a_src,
                                                const float* __restrict__ a_dst) {
  constexpr int C = (LAYER == 1) ? C1 : C2;
  const float* Hm = (LAYER == 1) ? g_h1 : g_h2;
  int t = blockIdx.x * 256 + threadIdx.x;
  if (t >= NN * NH) return;
  int n = t >> 3, h = t & 7;
  const float* row = &Hm[n * (NH * C) + h * C];
  float ss = 0.f, sd = 0.f;
#pragma unroll
  for (int c = 0; c < C; c++) {
    float v = row[c];
    ss = fmaf(v, a_src[h * C + c], ss);
    sd = fmaf(v, a_dst[h * C + c], sd);
  }
  g_ssrc[t] = ss;
  g_sdst[t] = sd;
}

// ---------------- layer-1 aggregation (wave per node, 64 channels) ----------------
__global__ __launch_bounds__(256) void agg1_kernel(const float* __restrict__ b1) {
  int gw = (blockIdx.x * 256 + threadIdx.x) >> 6;
  int lane = threadIdx.x & 63;
  if (gw >= NN) return;
  int n = gw;
  int hA = lane & 7;   // pass-A head (lane = e*8 + h)
  int hB = lane >> 3;  // pass-B head (lane = h*8 + c)
  float sdA = g_sdst[n * NH + hA];
  int begin = g_off[n], end = g_off[n + 1];
  int cnt = end - begin;
  // pass A: per-head denominator (self-loop counted once, in lanes 0..7)
  float dsum = 0.f;
  if (lane < 8) dsum = __expf(lrelu(g_ssrc[n * NH + hA] + sdA));
  for (int i = (lane >> 3); i < cnt; i += 8) {
    int src = g_csr[begin + i];
    dsum += __expf(lrelu(g_ssrc[src * NH + hA] + sdA));
  }
  dsum += __shfl_xor(dsum, 8);
  dsum += __shfl_xor(dsum, 16);
  dsum += __shfl_xor(dsum, 32);
  float inv = 1.f / __shfl(dsum, hB);  // lane r<8 holds denom of head r
  // pass B: accumulate all 64 channels
  float sdB = g_sdst[n * NH + hB];
  float acc = g_h1[n * HC1 + lane] * (__expf(lrelu(g_ssrc[n * NH + hB] + sdB)) * inv);
  for (int j0 = 0; j0 < cnt; j0 += 64) {
    int srcv = (j0 + lane < cnt) ? g_csr[begin + j0 + lane] : 0;
    int m = cnt - j0; if (m > 64) m = 64;
    for (int j = 0; j < m; j++) {
      int src = __shfl(srcv, j);
      float alpha = __expf(lrelu(g_ssrc[src * NH + hB] + sdB)) * inv;
      acc = fmaf(g_h1[src * HC1 + lane], alpha, acc);
    }
  }
  float v = acc + b1[lane];
  g_hact[n * HC1 + lane] = v > 0.f ? v : __expf(v) - 1.f;  // ELU
}

// ---------------- GEMM2: g_h2 = g_hact[NN,64] @ W2[64,80] ----------------
__global__ __launch_bounds__(256) void gemm2_kernel(const float* __restrict__ W) {
  __shared__ float sW[64 * HC2 + 64];
  int tid = threadIdx.x;
  for (int i = tid; i < 64 * HC2; i += 256) sW[i] = W[i];
  for (int i = 64 * HC2 + tid; i < 64 * HC2 + 64; i += 256) sW[i] = 0.f;
  __syncthreads();
  int lane = tid & 63;
  int w0 = (blockIdx.x * 256 + tid) >> 6;
  for (int r = w0; r < NN; r += 8192) {
    float v = g_hact[r * HC1 + lane];
    float acc0 = 0.f, acc1 = 0.f;
#pragma unroll
    for (int k = 0; k < 64; k++) {
      float xk = __shfl(v, k);
      acc0 = fmaf(xk, sW[k * HC2 + lane], acc0);
      acc1 = fmaf(xk, sW[k * HC2 + 64 + lane], acc1);
    }
    g_h2[r * HC2 + lane] = acc0;
    if (lane < 16) g_h2[r * HC2 + 64 + lane] = acc1;
  }
}

// ---------------- layer-2 aggregation (wave per node, 80 channels) ----------------
__global__ __launch_bounds__(256) void agg2_kernel(float* __restrict__ out) {
  int gw = (blockIdx.x * 256 + threadIdx.x) >> 6;
  int lane = threadIdx.x & 63;
  if (gw >= NN) return;
  int n = gw;
  int hA = lane & 7;
  float sdA = g_sdst[n * NH + hA];
  int begin = g_off[n], end = g_off[n + 1];
  int cnt = end - begin;
  float dsum = 0.f;
  if (lane < 8) dsum = __expf(lrelu(g_ssrc[n * NH + hA] + sdA));
  for (int i = (lane >> 3); i < cnt; i += 8) {
    int src = g_csr[begin + i];
    dsum += __expf(lrelu(g_ssrc[src * NH + hA] + sdA));
  }
  dsum += __shfl_xor(dsum, 8);
  dsum += __shfl_xor(dsum, 16);
  dsum += __shfl_xor(dsum, 32);
  int h0 = lane / 10;          // head of channel `lane`
  int h1 = (lane + 64) / 10;   // head of channel `lane+64` (lanes 0..15)
  float inv0 = 1.f / __shfl(dsum, h0);
  float inv1 = 1.f / __shfl(dsum, h1);
  float sd0 = g_sdst[n * NH + h0];
  float sd1 = g_sdst[n * NH + h1];
  bool hi = lane < (HC2 - 64);
  float acc0 = g_h2[n * HC2 + lane] * (__expf(lrelu(g_ssrc[n * NH + h0] + sd0)) * inv0);
  float acc1 = 0.f;
  if (hi) acc1 = g_h2[n * HC2 + 64 + lane] * (__expf(lrelu(g_ssrc[n * NH + h1] + sd1)) * inv1);
  for (int j0 = 0; j0 < cnt; j0 += 64) {
    int srcv = (j0 + lane < cnt) ? g_csr[begin + j0 + lane] : 0;
    int m = cnt - j0; if (m > 64) m = 64;
    for (int j = 0; j < m; j++) {
      int src = __shfl(srcv, j);
      float a0 = __expf(lrelu(g_ssrc[src * NH + h0] + sd0)) * inv0;
      acc0 = fmaf(g_h2[src * HC2 + lane], a0, acc0);
      if (hi) {
        float a1 = __expf(lrelu(g_ssrc[src * NH + h1] + sd1)) * inv1;
        acc1 = fmaf(g_h2[src * HC2 + 64 + lane], a1, acc1);
      }
    }
  }
  out[n * HC2 + lane] = acc0;
  if (hi) out[n * HC2 + 64 + lane] = acc1;
}

// ---------------- bias + log_softmax over 80 (in-place on d_out) ----------------
__global__ __launch_bounds__(256) void lsm_kernel(float* __restrict__ out,
                                                  const float* __restrict__ b2) {
  int gw = (blockIdx.x * 256 + threadIdx.x) >> 6;
  int lane = threadIdx.x & 63;
  if (gw >= NN) return;
  int n = gw;
  bool hi = lane < 16;
  float v0 = out[n * HC2 + lane] + b2[lane];
  float v1 = hi ? out[n * HC2 + 64 + lane] + b2[64 + lane] : -INFINITY;
  float mx = fmaxf(v0, v1);
  for (int o = 32; o; o >>= 1) mx = fmaxf(mx, __shfl_xor(mx, o));
  float s = __expf(v0 - mx) + (hi ? __expf(v1 - mx) : 0.f);
  for (int o = 32; o; o >>= 1) s += __shfl_xor(s, o);
  float lse = mx + __logf(s);
  out[n * HC2 + lane] = v0 - lse;
  if (hi) out[n * HC2 + 64 + lane] = v1 - lse;
}

// ---------------- launch ----------------
extern "C" void kernel_launch(void* const* d_in, const int* in_sizes, int n_in,
                              void* d_out, int out_size, void* d_ws, size_t ws_size,
                              hipStream_t stream) {
  (void)in_sizes; (void)n_in; (void)out_size; (void)d_ws; (void)ws_size;
  const float* x   = (const float*)d_in[0];
  const int*   ei  = (const int*)d_in[1];
  const float* W1  = (const float*)d_in[2];
  const float* as1 = (const float*)d_in[3];
  const float* ad1 = (const float*)d_in[4];
  const float* b1  = (const float*)d_in[5];
  const float* W2  = (const float*)d_in[6];
  const float* as2 = (const float*)d_in[7];
  const float* ad2 = (const float*)d_in[8];
  const float* b2  = (const float*)d_in[9];
  float* out = (float*)d_out;

  // CSR build (shared by both layers)
  zero_kernel<<<391, 256, 0, stream>>>();
  hist_kernel<<<12500, 256, 0, stream>>>(ei);
  scan_block_kernel<<<SCAN_NB, 256, 0, stream>>>();
  scan_tops_kernel<<<1, 128, 0, stream>>>();
  scan_add_kernel<<<391, 256, 0, stream>>>();
  scatter_kernel<<<12500, 256, 0, stream>>>(ei);

  // layer 1
  gemm1_kernel<<<1563, 256, 0, stream>>>(x, W1);
  s_kernel<1><<<3125, 256, 0, stream>>>(as1, ad1);
  agg1_kernel<<<25000, 256, 0, stream>>>(b1);

  // layer 2
  gemm2_kernel<<<2048, 256, 0, stream>>>(W2);
  s_kernel<2><<<3125, 256, 0, stream>>>(as2, ad2);
  agg2_kernel<<<25000, 256, 0, stream>>>(out);

  // epilogue
  lsm_kernel<<<25000, 256, 0, stream>>>(out, b2);
}

// Round 2
// 1074.960 us; speedup vs baseline: 1.2284x; 1.2284x over previous
//
#include <hip/hip_runtime.h>
#include <math.h>

#define NN 100000
#define NE 3200000
#define FIN 512
#define NH 8
#define C1 8
#define HC1 64
#define C2 10
#define HC2 80
#define SCAN_NB 98   // ceil(NN/1024)

// ---------------- static scratch ----------------
__device__ float g_h1[NN * HC1];        // x @ W1 (fp32)
__device__ float g_hact[NN * HC1];      // elu(agg1 + b1)
__device__ float g_h2[NN * HC2];        // hact @ W2 (fp32)
__device__ unsigned int g_h1b[NN * 32]; // h1 as bf16 pairs (ch 2p, 2p+1)
__device__ unsigned int g_h2b[NN * 40]; // h2 as bf16 pairs
__device__ float g_ssrc[NN * NH];
__device__ float g_sdst[NN * NH];
__device__ int   g_deg[NN];
__device__ int   g_cursor[NN];
__device__ int   g_off[NN + 1];
__device__ int   g_bsum[128];
__device__ int   g_csr[NE];

__device__ __forceinline__ float lrelu(float x) { return fmaxf(x, 0.2f * x); }

__device__ __forceinline__ unsigned int bf16_rne(float x) {
  unsigned int u = __float_as_uint(x);
  u += 0x7fffu + ((u >> 16) & 1u);
  return u >> 16;
}
__device__ __forceinline__ unsigned int packbf2(float lo, float hi) {
  return bf16_rne(lo) | (bf16_rne(hi) << 16);
}

// ---------------- CSR build ----------------
__global__ __launch_bounds__(256) void zero_kernel() {
  int i = blockIdx.x * 256 + threadIdx.x;
  if (i < NN) { g_deg[i] = 0; g_cursor[i] = 0; }
}

__global__ __launch_bounds__(256) void hist_kernel(const int* __restrict__ ei) {
  int e = blockIdx.x * 256 + threadIdx.x;
  if (e < NE) atomicAdd(&g_deg[ei[NE + e]], 1);
}

__global__ __launch_bounds__(256) void scan_block_kernel() {
  __shared__ int sd[256];
  int tid = threadIdx.x;
  int base = blockIdx.x * 1024 + tid * 4;
  int v0 = (base + 0 < NN) ? g_deg[base + 0] : 0;
  int v1 = (base + 1 < NN) ? g_deg[base + 1] : 0;
  int v2 = (base + 2 < NN) ? g_deg[base + 2] : 0;
  int v3 = (base + 3 < NN) ? g_deg[base + 3] : 0;
  int t1 = v0 + v1, t2 = t1 + v2, t3 = t2 + v3;
  sd[tid] = t3;
  __syncthreads();
  for (int off = 1; off < 256; off <<= 1) {
    int x = (tid >= off) ? sd[tid - off] : 0;
    __syncthreads();
    sd[tid] += x;
    __syncthreads();
  }
  int excl = sd[tid] - t3;
  if (base + 0 < NN) g_off[base + 1] = excl + v0;
  if (base + 1 < NN) g_off[base + 2] = excl + t1;
  if (base + 2 < NN) g_off[base + 3] = excl + t2;
  if (base + 3 < NN) g_off[base + 4] = excl + t3;
  if (tid == 255) g_bsum[blockIdx.x] = sd[255];
}

__global__ void scan_tops_kernel() {  // 1 block, 128 threads
  __shared__ int sd[128];
  int tid = threadIdx.x;
  int v = (tid < SCAN_NB) ? g_bsum[tid] : 0;
  sd[tid] = v;
  __syncthreads();
  for (int off = 1; off < 128; off <<= 1) {
    int x = (tid >= off) ? sd[tid - off] : 0;
    __syncthreads();
    sd[tid] += x;
    __syncthreads();
  }
  g_bsum[tid] = sd[tid] - v;  // exclusive scan of block sums
  if (tid == 0) g_off[0] = 0;
}

__global__ __launch_bounds__(256) void scan_add_kernel() {
  int i = blockIdx.x * 256 + threadIdx.x;
  if (i < NN) g_off[i + 1] += g_bsum[i >> 10];
}

__global__ __launch_bounds__(256) void scatter_kernel(const int* __restrict__ ei) {
  int e = blockIdx.x * 256 + threadIdx.x;
  if (e < NE) {
    int s = ei[e], d = ei[NE + e];
    int pos = g_off[d] + atomicAdd(&g_cursor[d], 1);
    g_csr[pos] = s;
  }
}

// ---------------- GEMM1: g_h1 = X[NN,512] @ W1[512,64] (fp32 tiled) ----------------
__global__ __launch_bounds__(256) void gemm1_kernel(const float* __restrict__ X,
                                                    const float* __restrict__ W) {
  __shared__ float sA[64][64];  // [m][k]
  __shared__ float sB[64][64];  // [k][n]
  int tid = threadIdx.x;
  int r0 = blockIdx.x * 64;
  int tx = tid & 15, ty = tid >> 4;
  int lrow = tid >> 4;
  int lc4 = tid & 15;
  float acc[4][4] = {{0.f, 0.f, 0.f, 0.f}};
  for (int k0 = 0; k0 < FIN; k0 += 64) {
#pragma unroll
    for (int rr = 0; rr < 4; rr++) {
      int m = lrow + rr * 16;
      int row = r0 + m; if (row >= NN) row = NN - 1;
      float4 v = *(const float4*)&X[row * FIN + k0 + lc4 * 4];
      *(float4*)&sA[m][lc4 * 4] = v;
      float4 w = *(const float4*)&W[(k0 + m) * HC1 + lc4 * 4];
      *(float4*)&sB[m][lc4 * 4] = w;
    }
    __syncthreads();
#pragma unroll
    for (int kk = 0; kk < 64; kk += 4) {
      float4 a4[4];
#pragma unroll
      for (int i = 0; i < 4; i++) a4[i] = *(const float4*)&sA[ty * 4 + i][kk];
#pragma unroll
      for (int c = 0; c < 4; c++) {
        float4 b = *(const float4*)&sB[kk + c][tx * 4];
#pragma unroll
        for (int i = 0; i < 4; i++) {
          float a = (c == 0) ? a4[i].x : (c == 1) ? a4[i].y : (c == 2) ? a4[i].z : a4[i].w;
          acc[i][0] = fmaf(a, b.x, acc[i][0]);
          acc[i][1] = fmaf(a, b.y, acc[i][1]);
          acc[i][2] = fmaf(a, b.z, acc[i][2]);
          acc[i][3] = fmaf(a, b.w, acc[i][3]);
        }
      }
    }
    __syncthreads();
  }
#pragma unroll
  for (int i = 0; i < 4; i++) {
    int row = r0 + ty * 4 + i;
    if (row < NN) {
      float4 v = make_float4(acc[i][0], acc[i][1], acc[i][2], acc[i][3]);
      *(float4*)&g_h1[row * HC1 + tx * 4] = v;
    }
  }
}

// ---------------- attention scores + bf16 packing ----------------
template <int LAYER>
__global__ __launch_bounds__(256) void s_kernel(const float* __restrict__ a_src,
                                                const float* __restrict__ a_dst) {
  constexpr int C = (LAYER == 1) ? C1 : C2;
  const float* Hm = (LAYER == 1) ? g_h1 : g_h2;
  unsigned int* Hb = (LAYER == 1) ? g_h1b : g_h2b;
  int t = blockIdx.x * 256 + threadIdx.x;
  if (t >= NN * NH) return;
  int n = t >> 3, h = t & 7;
  const float* row = &Hm[(n * NH + h) * C];
  float ss = 0.f, sdd = 0.f;
  float vals[C];
#pragma unroll
  for (int c = 0; c < C; c++) {
    float v = row[c];
    vals[c] = v;
    ss = fmaf(v, a_src[h * C + c], ss);
    sdd = fmaf(v, a_dst[h * C + c], sdd);
  }
  g_ssrc[t] = ss;
  g_sdst[t] = sdd;
#pragma unroll
  for (int j = 0; j < C / 2; j++)
    Hb[(n * NH + h) * (C / 2) + j] = packbf2(vals[2 * j], vals[2 * j + 1]);
}

// ---------------- layer-1 aggregation: merged softmax + gather (bf16 msgs) ----------
// wave per node; lane = (half, pair): pair p covers channels 2p,2p+1; head = p>>2.
// two edges processed per iteration (one per half-wave).
__global__ __launch_bounds__(256) void agg1_kernel(const float* __restrict__ b1) {
  int gw = (blockIdx.x * 256 + threadIdx.x) >> 6;
  if (gw >= NN) return;
  int lane = threadIdx.x & 63;
  int half = lane >> 5;
  int p = lane & 31;
  int h = p >> 2;
  float sd = g_sdst[gw * NH + h];
  int begin = g_off[gw];
  int cnt = g_off[gw + 1] - begin;
  float acc0 = 0.f, acc1 = 0.f, wsum = 0.f;
  for (int j0 = 0; j0 < cnt; j0 += 64) {
    int m = cnt - j0; if (m > 64) m = 64;
    int srcv = (lane < m) ? g_csr[begin + j0 + lane] : 0;
    int me = m & ~1;
    for (int j = 0; j < me; j += 2) {
      int src = __shfl(srcv, j + half);
      float e = __expf(lrelu(g_ssrc[src * NH + h] + sd));
      unsigned int v = g_h1b[src * 32 + p];
      acc0 = fmaf(__uint_as_float(v << 16), e, acc0);
      acc1 = fmaf(__uint_as_float(v & 0xffff0000u), e, acc1);
      wsum += e;
    }
    if (me < m) {  // odd tail edge: half 0 contributes, half 1 zeroed
      int src = __shfl(srcv, me);
      float e = (half == 0) ? __expf(lrelu(g_ssrc[src * NH + h] + sd)) : 0.f;
      unsigned int v = g_h1b[src * 32 + p];
      acc0 = fmaf(__uint_as_float(v << 16), e, acc0);
      acc1 = fmaf(__uint_as_float(v & 0xffff0000u), e, acc1);
      wsum += e;
    }
  }
  acc0 += __shfl_xor(acc0, 32);
  acc1 += __shfl_xor(acc1, 32);
  wsum += __shfl_xor(wsum, 32);
  // self loop (fp32)
  float es = __expf(lrelu(g_ssrc[gw * NH + h] + sd));
  acc0 = fmaf(g_h1[gw * HC1 + 2 * p], es, acc0);
  acc1 = fmaf(g_h1[gw * HC1 + 2 * p + 1], es, acc1);
  wsum += es;
  if (half == 0) {
    float inv = 1.f / wsum;
    float v0 = acc0 * inv + b1[2 * p];
    float v1 = acc1 * inv + b1[2 * p + 1];
    v0 = v0 > 0.f ? v0 : __expf(v0) - 1.f;  // ELU
    v1 = v1 > 0.f ? v1 : __expf(v1) - 1.f;
    *(float2*)&g_hact[gw * HC1 + 2 * p] = make_float2(v0, v1);
  }
}

// ---------------- GEMM2: g_h2 = g_hact[NN,64] @ W2[64,80] ----------------
__global__ __launch_bounds__(256) void gemm2_kernel(const float* __restrict__ W) {
  __shared__ float sW[64 * HC2 + 64];
  int tid = threadIdx.x;
  for (int i = tid; i < 64 * HC2; i += 256) sW[i] = W[i];
  for (int i = 64 * HC2 + tid; i < 64 * HC2 + 64; i += 256) sW[i] = 0.f;
  __syncthreads();
  int lane = tid & 63;
  int w0 = (blockIdx.x * 256 + tid) >> 6;
  for (int r = w0; r < NN; r += 8192) {
    float v = g_hact[r * HC1 + lane];
    float acc0 = 0.f, acc1 = 0.f;
#pragma unroll
    for (int k = 0; k < 64; k++) {
      float xk = __shfl(v, k);
      acc0 = fmaf(xk, sW[k * HC2 + lane], acc0);
      acc1 = fmaf(xk, sW[k * HC2 + 64 + lane], acc1);
    }
    g_h2[r * HC2 + lane] = acc0;
    if (lane < 16) g_h2[r * HC2 + 64 + lane] = acc1;
  }
}

// ------- layer-2 aggregation, merged softmax + gather + bias + log_softmax -------
// wave per node; pair-lanes 0..39 (pair p = channels 2p,2p+1; head = p/5, pairs
// never straddle heads since heads are 10 channels). lanes 40..63 mirror pair 39.
__global__ __launch_bounds__(256) void agg2_kernel(float* __restrict__ out,
                                                   const float* __restrict__ b2) {
  int gw = (blockIdx.x * 256 + threadIdx.x) >> 6;
  if (gw >= NN) return;
  int lane = threadIdx.x & 63;
  int p = lane < 40 ? lane : 39;
  int h = p / 5;
  float sd = g_sdst[gw * NH + h];
  int begin = g_off[gw];
  int cnt = g_off[gw + 1] - begin;
  float acc0 = 0.f, acc1 = 0.f, wsum = 0.f;
  for (int j0 = 0; j0 < cnt; j0 += 64) {
    int m = cnt - j0; if (m > 64) m = 64;
    int srcv = (lane < m) ? g_csr[begin + j0 + lane] : 0;
    for (int j = 0; j < m; j++) {
      int src = __shfl(srcv, j);
      float e = __expf(lrelu(g_ssrc[src * NH + h] + sd));
      unsigned int v = g_h2b[src * 40 + p];
      acc0 = fmaf(__uint_as_float(v << 16), e, acc0);
      acc1 = fmaf(__uint_as_float(v & 0xffff0000u), e, acc1);
      wsum += e;
    }
  }
  float es = __expf(lrelu(g_ssrc[gw * NH + h] + sd));
  acc0 = fmaf(g_h2[gw * HC2 + 2 * p], es, acc0);
  acc1 = fmaf(g_h2[gw * HC2 + 2 * p + 1], es, acc1);
  wsum += es;
  float inv = 1.f / wsum;
  float v0 = acc0 * inv + b2[2 * p];
  float v1 = acc1 * inv + b2[2 * p + 1];
  // fused log_softmax over 80 channels (lanes >=40 duplicate pair 39: max ok, sum masked)
  float mx = fmaxf(v0, v1);
  for (int o = 32; o; o >>= 1) mx = fmaxf(mx, __shfl_xor(mx, o));
  float spart = (lane < 40) ? __expf(v0 - mx) + __expf(v1 - mx) : 0.f;
  for (int o = 32; o; o >>= 1) spart += __shfl_xor(spart, o);
  float lse = mx + __logf(spart);
  if (lane < 40) *(float2*)&out[gw * HC2 + 2 * p] = make_float2(v0 - lse, v1 - lse);
}

// ---------------- launch ----------------
extern "C" void kernel_launch(void* const* d_in, const int* in_sizes, int n_in,
                              void* d_out, int out_size, void* d_ws, size_t ws_size,
                              hipStream_t stream) {
  (void)in_sizes; (void)n_in; (void)out_size; (void)d_ws; (void)ws_size;
  const float* x   = (const float*)d_in[0];
  const int*   ei  = (const int*)d_in[1];
  const float* W1  = (const float*)d_in[2];
  const float* as1 = (const float*)d_in[3];
  const float* ad1 = (const float*)d_in[4];
  const float* b1  = (const float*)d_in[5];
  const float* W2  = (const float*)d_in[6];
  const float* as2 = (const float*)d_in[7];
  const float* ad2 = (const float*)d_in[8];
  const float* b2  = (const float*)d_in[9];
  float* out = (float*)d_out;

  // CSR build (shared by both layers)
  zero_kernel<<<391, 256, 0, stream>>>();
  hist_kernel<<<12500, 256, 0, stream>>>(ei);
  scan_block_kernel<<<SCAN_NB, 256, 0, stream>>>();
  scan_tops_kernel<<<1, 128, 0, stream>>>();
  scan_add_kernel<<<391, 256, 0, stream>>>();
  scatter_kernel<<<12500, 256, 0, stream>>>(ei);

  // layer 1
  gemm1_kernel<<<1563, 256, 0, stream>>>(x, W1);
  s_kernel<1><<<3125, 256, 0, stream>>>(as1, ad1);
  agg1_kernel<<<25000, 256, 0, stream>>>(b1);

  // layer 2
  gemm2_kernel<<<2048, 256, 0, stream>>>(W2);
  s_kernel<2><<<3125, 256, 0, stream>>>(as2, ad2);
  agg2_kernel<<<25000, 256, 0, stream>>>(out, b2);
}

// Round 3
// 920.316 us; speedup vs baseline: 1.4348x; 1.1680x over previous
//
#include <hip/hip_runtime.h>
#include <math.h>

#define NN 100000
#define NE 3200000
#define FIN 512
#define NH 8
#define C1 8
#define HC1 64
#define C2 10
#define HC2 80
#define SCAN_NB 98   // ceil(NN/1024)

typedef unsigned int uint;
using bf16x8 = __attribute__((ext_vector_type(8))) short;
using f32x4  = __attribute__((ext_vector_type(4))) float;

// ---------------- static scratch ----------------
__device__ float g_h1[NN * HC1];        // x @ W1 (fp32, MFMA out)
__device__ float g_hact[NN * HC1];      // elu(agg1 + b1)
__device__ float g_h2[NN * HC2];        // hact @ W2 (fp32)
__device__ uint  g_h1b[NN * 32];        // h1 as bf16 pairs (ch 2p, 2p+1)
__device__ uint  g_h2b[NN * 40];        // h2 as bf16 pairs
__device__ uint  g_w1bt[64 * 256];      // W1 transposed bf16 pairs: [n][kp]
__device__ float g_ssrc[NN * NH];
__device__ float g_sdst[NN * NH];
__device__ int   g_deg[NN];
__device__ int   g_off[NN + 1];
__device__ int   g_bsum[128];
__device__ int   g_rank[NE];            // rank of edge within its dst (from hist)
__device__ int   g_csr[NE];

__device__ __forceinline__ float lrelu(float x) { return fmaxf(x, 0.2f * x); }

__device__ __forceinline__ uint bf16_rne(float x) {
  uint u = __float_as_uint(x);
  u += 0x7fffu + ((u >> 16) & 1u);
  return u >> 16;
}
__device__ __forceinline__ uint packbf2(float lo, float hi) {
  return bf16_rne(lo) | (bf16_rne(hi) << 16);
}
__device__ __forceinline__ float blo(uint v) { return __uint_as_float(v << 16); }
__device__ __forceinline__ float bhi(uint v) { return __uint_as_float(v & 0xffff0000u); }

// ---------------- CSR build ----------------
__global__ __launch_bounds__(256) void zero_kernel() {
  int i = blockIdx.x * 256 + threadIdx.x;
  if (i < NN) g_deg[i] = 0;
}

__global__ __launch_bounds__(256) void hist_kernel(const int* __restrict__ ei) {
  int e = blockIdx.x * 256 + threadIdx.x;
  if (e < NE) g_rank[e] = atomicAdd(&g_deg[ei[NE + e]], 1);
}

__global__ __launch_bounds__(256) void scan_block_kernel() {
  __shared__ int sd[256];
  int tid = threadIdx.x;
  int base = blockIdx.x * 1024 + tid * 4;
  int v0 = (base + 0 < NN) ? g_deg[base + 0] : 0;
  int v1 = (base + 1 < NN) ? g_deg[base + 1] : 0;
  int v2 = (base + 2 < NN) ? g_deg[base + 2] : 0;
  int v3 = (base + 3 < NN) ? g_deg[base + 3] : 0;
  int t1 = v0 + v1, t2 = t1 + v2, t3 = t2 + v3;
  sd[tid] = t3;
  __syncthreads();
  for (int off = 1; off < 256; off <<= 1) {
    int x = (tid >= off) ? sd[tid - off] : 0;
    __syncthreads();
    sd[tid] += x;
    __syncthreads();
  }
  int excl = sd[tid] - t3;
  if (base + 0 < NN) g_off[base + 1] = excl + v0;
  if (base + 1 < NN) g_off[base + 2] = excl + t1;
  if (base + 2 < NN) g_off[base + 3] = excl + t2;
  if (base + 3 < NN) g_off[base + 4] = excl + t3;
  if (tid == 255) g_bsum[blockIdx.x] = sd[255];
}

__global__ void scan_tops_kernel() {  // 1 block, 128 threads
  __shared__ int sd[128];
  int tid = threadIdx.x;
  int v = (tid < SCAN_NB) ? g_bsum[tid] : 0;
  sd[tid] = v;
  __syncthreads();
  for (int off = 1; off < 128; off <<= 1) {
    int x = (tid >= off) ? sd[tid - off] : 0;
    __syncthreads();
    sd[tid] += x;
    __syncthreads();
  }
  g_bsum[tid] = sd[tid] - v;  // exclusive scan of block sums
  if (tid == 0) g_off[0] = 0;
}

__global__ __launch_bounds__(256) void scan_add_kernel() {
  int i = blockIdx.x * 256 + threadIdx.x;
  if (i < NN) g_off[i + 1] += g_bsum[i >> 10];
}

__global__ __launch_bounds__(256) void scatter_kernel(const int* __restrict__ ei) {
  int e = blockIdx.x * 256 + threadIdx.x;
  if (e < NE) g_csr[g_off[ei[NE + e]] + g_rank[e]] = ei[e];  // atomic-free
}

// ---------------- W1 -> bf16 transposed pairs ----------------
__global__ __launch_bounds__(256) void w1cast_kernel(const float* __restrict__ W) {
  int idx = blockIdx.x * 256 + threadIdx.x;  // 0..16383
  int n = idx & 63, kp = idx >> 6;           // kp 0..255
  float lo = W[(2 * kp) * HC1 + n];
  float hi = W[(2 * kp + 1) * HC1 + n];
  g_w1bt[n * 256 + kp] = packbf2(lo, hi);
}

// ---------------- GEMM1: g_h1 = X[NN,512] @ W1[512,64] via bf16 MFMA ------------
// block = 256 thr (4 waves); tile M=64 (16 rows/wave), N=64 (4 mfma col-tiles).
// LDS uint[64][32] bf16-pair tiles, XOR group-swizzle (grp^=(row&7)) -> <=2-way.
__device__ __forceinline__ int sw_idx(int row, int g) {
  return row * 32 + ((g ^ (row & 7)) << 2);
}

__global__ __launch_bounds__(256) void gemm1_kernel(const float* __restrict__ X) {
  __shared__ uint sA[64 * 32];
  __shared__ uint sB[64 * 32];
  int t = threadIdx.x;
  int w = t >> 6, l = t & 63;
  int q = l >> 4, c = l & 15;
  int r0 = blockIdx.x * 64;
  // staging coords
  int sr = t >> 2;             // 0..63 (row / n)
  int sc = t & 3;              // quarter
  int xrow = r0 + sr; if (xrow >= NN) xrow = NN - 1;
  const float* xbase = &X[(long)xrow * FIN + sc * 16];
  const uint* wbase = &g_w1bt[sr * 256 + sc * 8];
  f32x4 acc[4] = {{0.f,0.f,0.f,0.f},{0.f,0.f,0.f,0.f},{0.f,0.f,0.f,0.f},{0.f,0.f,0.f,0.f}};
  for (int k0 = 0; k0 < FIN; k0 += 64) {
    __syncthreads();
    // stage A: 64 rows x 64 k (fp32 -> bf16 pairs)
    float4 f0 = *(const float4*)&xbase[k0 + 0];
    float4 f1 = *(const float4*)&xbase[k0 + 4];
    float4 f2 = *(const float4*)&xbase[k0 + 8];
    float4 f3 = *(const float4*)&xbase[k0 + 12];
    uint4 a0 = make_uint4(packbf2(f0.x, f0.y), packbf2(f0.z, f0.w),
                          packbf2(f1.x, f1.y), packbf2(f1.z, f1.w));
    uint4 a1 = make_uint4(packbf2(f2.x, f2.y), packbf2(f2.z, f2.w),
                          packbf2(f3.x, f3.y), packbf2(f3.z, f3.w));
    *(uint4*)&sA[sw_idx(sr, sc * 2 + 0)] = a0;
    *(uint4*)&sA[sw_idx(sr, sc * 2 + 1)] = a1;
    // stage B: 64 n x 64 k from pre-packed transposed W1
    uint4 b0 = *(const uint4*)&wbase[(k0 >> 1) + 0];
    uint4 b1 = *(const uint4*)&wbase[(k0 >> 1) + 4];
    *(uint4*)&sB[sw_idx(sr, sc * 2 + 0)] = b0;
    *(uint4*)&sB[sw_idx(sr, sc * 2 + 1)] = b1;
    __syncthreads();
#pragma unroll
    for (int ks = 0; ks < 2; ks++) {
      int g = ks * 4 + q;
      bf16x8 a = *(const bf16x8*)&sA[sw_idx(w * 16 + c, g)];
#pragma unroll
      for (int nt = 0; nt < 4; nt++) {
        bf16x8 b = *(const bf16x8*)&sB[sw_idx(nt * 16 + c, g)];
        acc[nt] = __builtin_amdgcn_mfma_f32_16x16x32_bf16(a, b, acc[nt], 0, 0, 0);
      }
    }
  }
  int orow0 = r0 + w * 16 + q * 4;
#pragma unroll
  for (int nt = 0; nt < 4; nt++) {
#pragma unroll
    for (int r = 0; r < 4; r++) {
      int row = orow0 + r;
      if (row < NN) g_h1[row * HC1 + nt * 16 + c] = acc[nt][r];
    }
  }
}

// ---------------- attention scores + bf16 packing ----------------
template <int LAYER>
__global__ __launch_bounds__(256) void s_kernel(const float* __restrict__ a_src,
                                                const float* __restrict__ a_dst) {
  constexpr int C = (LAYER == 1) ? C1 : C2;
  const float* Hm = (LAYER == 1) ? g_h1 : g_h2;
  uint* Hb = (LAYER == 1) ? g_h1b : g_h2b;
  int t = blockIdx.x * 256 + threadIdx.x;
  if (t >= NN * NH) return;
  int h = t & 7;
  const float* row = &Hm[t * C];
  float ss = 0.f, sdd = 0.f;
  float vals[C];
#pragma unroll
  for (int c = 0; c < C; c++) {
    float v = row[c];
    vals[c] = v;
    ss = fmaf(v, a_src[h * C + c], ss);
    sdd = fmaf(v, a_dst[h * C + c], sdd);
  }
  g_ssrc[t] = ss;
  g_sdst[t] = sdd;
#pragma unroll
  for (int j = 0; j < C / 2; j++)
    Hb[t * (C / 2) + j] = packbf2(vals[2 * j], vals[2 * j + 1]);
}

// ---------------- layer-1 aggregation (bf16 msgs, 4-edge unroll) ----------------
// wave per node; lane = (half, pair p): pair p = channels 2p,2p+1; head = p>>2.
__global__ __launch_bounds__(256) void agg1_kernel(const float* __restrict__ b1) {
  int gw = (blockIdx.x * 256 + threadIdx.x) >> 6;
  if (gw >= NN) return;
  int lane = threadIdx.x & 63;
  int half = lane >> 5;
  int p = lane & 31;
  int h = p >> 2;
  float sd = g_sdst[gw * NH + h];
  int begin = g_off[gw];
  int cnt = g_off[gw + 1] - begin;
  float acc0 = 0.f, acc1 = 0.f, wsum = 0.f;
  for (int j0 = 0; j0 < cnt; j0 += 64) {
    int m = cnt - j0; if (m > 64) m = 64;
    int srcv = (lane < m) ? g_csr[begin + j0 + lane] : 0;
    int j = 0;
    for (; j + 4 <= m; j += 4) {  // 4 edges: 2 per half-wave, loads batched
      int sa = __shfl(srcv, j + half);
      int sb = __shfl(srcv, j + 2 + half);
      float ta = g_ssrc[sa * NH + h];
      float tb = g_ssrc[sb * NH + h];
      uint va = g_h1b[sa * 32 + p];
      uint vb = g_h1b[sb * 32 + p];
      float ea = __expf(lrelu(ta + sd));
      float eb = __expf(lrelu(tb + sd));
      acc0 = fmaf(blo(va), ea, acc0); acc1 = fmaf(bhi(va), ea, acc1);
      acc0 = fmaf(blo(vb), eb, acc0); acc1 = fmaf(bhi(vb), eb, acc1);
      wsum += ea + eb;
    }
    for (; j + 2 <= m; j += 2) {
      int s = __shfl(srcv, j + half);
      float e = __expf(lrelu(g_ssrc[s * NH + h] + sd));
      uint v = g_h1b[s * 32 + p];
      acc0 = fmaf(blo(v), e, acc0); acc1 = fmaf(bhi(v), e, acc1);
      wsum += e;
    }
    if (j < m) {  // odd tail edge: half 0 contributes, half 1 zeroed
      int s = __shfl(srcv, j);
      float e = (half == 0) ? __expf(lrelu(g_ssrc[s * NH + h] + sd)) : 0.f;
      uint v = g_h1b[s * 32 + p];
      acc0 = fmaf(blo(v), e, acc0); acc1 = fmaf(bhi(v), e, acc1);
      wsum += e;
    }
  }
  acc0 += __shfl_xor(acc0, 32);
  acc1 += __shfl_xor(acc1, 32);
  wsum += __shfl_xor(wsum, 32);
  // self loop (fp32)
  float es = __expf(lrelu(g_ssrc[gw * NH + h] + sd));
  acc0 = fmaf(g_h1[gw * HC1 + 2 * p], es, acc0);
  acc1 = fmaf(g_h1[gw * HC1 + 2 * p + 1], es, acc1);
  wsum += es;
  if (half == 0) {
    float inv = 1.f / wsum;
    float v0 = acc0 * inv + b1[2 * p];
    float v1 = acc1 * inv + b1[2 * p + 1];
    v0 = v0 > 0.f ? v0 : __expf(v0) - 1.f;  // ELU
    v1 = v1 > 0.f ? v1 : __expf(v1) - 1.f;
    *(float2*)&g_hact[gw * HC1 + 2 * p] = make_float2(v0, v1);
  }
}

// ---------------- GEMM2: g_h2 = g_hact[NN,64] @ W2[64,80] ----------------
__global__ __launch_bounds__(256) void gemm2_kernel(const float* __restrict__ W) {
  __shared__ float sW[64 * HC2 + 64];
  int tid = threadIdx.x;
  for (int i = tid; i < 64 * HC2; i += 256) sW[i] = W[i];
  for (int i = 64 * HC2 + tid; i < 64 * HC2 + 64; i += 256) sW[i] = 0.f;
  __syncthreads();
  int lane = tid & 63;
  int w0 = (blockIdx.x * 256 + tid) >> 6;
  for (int r = w0; r < NN; r += 8192) {
    float v = g_hact[r * HC1 + lane];
    float acc0 = 0.f, acc1 = 0.f;
#pragma unroll
    for (int k = 0; k < 64; k++) {
      float xk = __shfl(v, k);
      acc0 = fmaf(xk, sW[k * HC2 + lane], acc0);
      acc1 = fmaf(xk, sW[k * HC2 + 64 + lane], acc1);
    }
    g_h2[r * HC2 + lane] = acc0;
    if (lane < 16) g_h2[r * HC2 + 64 + lane] = acc1;
  }
}

// ------- layer-2 aggregation: softmax + gather + bias + log_softmax, 4x unroll ----
__global__ __launch_bounds__(256) void agg2_kernel(float* __restrict__ out,
                                                   const float* __restrict__ b2) {
  int gw = (blockIdx.x * 256 + threadIdx.x) >> 6;
  if (gw >= NN) return;
  int lane = threadIdx.x & 63;
  int p = lane < 40 ? lane : 39;
  int h = p / 5;
  float sd = g_sdst[gw * NH + h];
  int begin = g_off[gw];
  int cnt = g_off[gw + 1] - begin;
  float acc0 = 0.f, acc1 = 0.f, wsum = 0.f;
  for (int j0 = 0; j0 < cnt; j0 += 64) {
    int m = cnt - j0; if (m > 64) m = 64;
    int srcv = (lane < m) ? g_csr[begin + j0 + lane] : 0;
    int j = 0;
    for (; j + 4 <= m; j += 4) {  // 4 edges in flight
      int s0 = __shfl(srcv, j);
      int s1 = __shfl(srcv, j + 1);
      int s2 = __shfl(srcv, j + 2);
      int s3 = __shfl(srcv, j + 3);
      float t0 = g_ssrc[s0 * NH + h];
      float t1 = g_ssrc[s1 * NH + h];
      float t2 = g_ssrc[s2 * NH + h];
      float t3 = g_ssrc[s3 * NH + h];
      uint v0 = g_h2b[s0 * 40 + p];
      uint v1 = g_h2b[s1 * 40 + p];
      uint v2 = g_h2b[s2 * 40 + p];
      uint v3 = g_h2b[s3 * 40 + p];
      float e0 = __expf(lrelu(t0 + sd));
      float e1 = __expf(lrelu(t1 + sd));
      float e2 = __expf(lrelu(t2 + sd));
      float e3 = __expf(lrelu(t3 + sd));
      acc0 = fmaf(blo(v0), e0, acc0); acc1 = fmaf(bhi(v0), e0, acc1);
      acc0 = fmaf(blo(v1), e1, acc0); acc1 = fmaf(bhi(v1), e1, acc1);
      acc0 = fmaf(blo(v2), e2, acc0); acc1 = fmaf(bhi(v2), e2, acc1);
      acc0 = fmaf(blo(v3), e3, acc0); acc1 = fmaf(bhi(v3), e3, acc1);
      wsum += (e0 + e1) + (e2 + e3);
    }
    for (; j < m; j++) {
      int s = __shfl(srcv, j);
      float e = __expf(lrelu(g_ssrc[s * NH + h] + sd));
      uint v = g_h2b[s * 40 + p];
      acc0 = fmaf(blo(v), e, acc0); acc1 = fmaf(bhi(v), e, acc1);
      wsum += e;
    }
  }
  float es = __expf(lrelu(g_ssrc[gw * NH + h] + sd));
  acc0 = fmaf(g_h2[gw * HC2 + 2 * p], es, acc0);
  acc1 = fmaf(g_h2[gw * HC2 + 2 * p + 1], es, acc1);
  wsum += es;
  float inv = 1.f / wsum;
  float v0 = acc0 * inv + b2[2 * p];
  float v1 = acc1 * inv + b2[2 * p + 1];
  // fused log_softmax over 80 channels (lanes >=40 duplicate pair 39: max ok, sum masked)
  float mx = fmaxf(v0, v1);
  for (int o = 32; o; o >>= 1) mx = fmaxf(mx, __shfl_xor(mx, o));
  float spart = (lane < 40) ? __expf(v0 - mx) + __expf(v1 - mx) : 0.f;
  for (int o = 32; o; o >>= 1) spart += __shfl_xor(spart, o);
  float lse = mx + __logf(spart);
  if (lane < 40) *(float2*)&out[gw * HC2 + 2 * p] = make_float2(v0 - lse, v1 - lse);
}

// ---------------- launch ----------------
extern "C" void kernel_launch(void* const* d_in, const int* in_sizes, int n_in,
                              void* d_out, int out_size, void* d_ws, size_t ws_size,
                              hipStream_t stream) {
  (void)in_sizes; (void)n_in; (void)out_size; (void)d_ws; (void)ws_size;
  const float* x   = (const float*)d_in[0];
  const int*   ei  = (const int*)d_in[1];
  const float* W1  = (const float*)d_in[2];
  const float* as1 = (const float*)d_in[3];
  const float* ad1 = (const float*)d_in[4];
  const float* b1  = (const float*)d_in[5];
  const float* W2  = (const float*)d_in[6];
  const float* as2 = (const float*)d_in[7];
  const float* ad2 = (const float*)d_in[8];
  const float* b2  = (const float*)d_in[9];
  float* out = (float*)d_out;

  // CSR build (shared by both layers)
  zero_kernel<<<391, 256, 0, stream>>>();
  hist_kernel<<<12500, 256, 0, stream>>>(ei);
  scan_block_kernel<<<SCAN_NB, 256, 0, stream>>>();
  scan_tops_kernel<<<1, 128, 0, stream>>>();
  scan_add_kernel<<<391, 256, 0, stream>>>();
  scatter_kernel<<<12500, 256, 0, stream>>>(ei);

  // layer 1
  w1cast_kernel<<<64, 256, 0, stream>>>(W1);
  gemm1_kernel<<<1563, 256, 0, stream>>>(x);
  s_kernel<1><<<3125, 256, 0, stream>>>(as1, ad1);
  agg1_kernel<<<25000, 256, 0, stream>>>(b1);

  // layer 2
  gemm2_kernel<<<2048, 256, 0, stream>>>(W2);
  s_kernel<2><<<3125, 256, 0, stream>>>(as2, ad2);
  agg2_kernel<<<25000, 256, 0, stream>>>(out, b2);
}

// Round 4
// 792.544 us; speedup vs baseline: 1.6661x; 1.1612x over previous
//
#include <hip/hip_runtime.h>
#include <math.h>

#define NN 100000
#define NE 3200000
#define FIN 512
#define NH 8
#define C1 8
#define HC1 64
#define C2 10
#define HC2 80

// radix CSR build
#define EPB 4096
#define NBLK 782           // ceil(NE/EPB)
#define NBUK 196           // ceil(NN/512)
#define SCN (NBUK * NBLK)  // 153272
#define SCNB 150           // ceil(SCN/1024)

typedef unsigned int uint;
using bf16x8 = __attribute__((ext_vector_type(8))) short;
using f32x4  = __attribute__((ext_vector_type(4))) float;

// ---------------- static scratch ----------------
__device__ float g_h1[NN * HC1];        // x @ W1 (fp32, MFMA out)
__device__ float g_hact[NN * HC1];      // elu(agg1 + b1)
__device__ float g_h2[NN * HC2];        // hact @ W2 (fp32)
__device__ uint  g_h1b[NN * 32];        // h1 as bf16 pairs (ch 2p, 2p+1)
__device__ uint  g_h2b[NN * 40];        // h2 as bf16 pairs
__device__ uint  g_w1bt[64 * 256];      // W1 transposed bf16 pairs: [n][kp]
__device__ float g_ssrc[NN * NH];
__device__ float g_sdst[NN * NH];
__device__ int   g_off[NN + 1];
__device__ uint  g_pscan[SCN];          // per-(bucket,block) counts -> scanned
__device__ uint  g_bsum2[256];
__device__ uint  g_ebuf[NE];            // packed (dlow<<17)|src, bucket-partitioned
__device__ int   g_csr[NE];

__device__ __forceinline__ float lrelu(float x) { return fmaxf(x, 0.2f * x); }

__device__ __forceinline__ uint bf16_rne(float x) {
  uint u = __float_as_uint(x);
  u += 0x7fffu + ((u >> 16) & 1u);
  return u >> 16;
}
__device__ __forceinline__ uint packbf2(float lo, float hi) {
  return bf16_rne(lo) | (bf16_rne(hi) << 16);
}
__device__ __forceinline__ float blo(uint v) { return __uint_as_float(v << 16); }
__device__ __forceinline__ float bhi(uint v) { return __uint_as_float(v & 0xffff0000u); }

// ---------------- CSR build: radix partition by dst, no global atomics ----------
__global__ __launch_bounds__(256) void p1count_kernel(const int* __restrict__ ei) {
  __shared__ uint cnt[NBUK];
  int tid = threadIdx.x;
  for (int i = tid; i < NBUK; i += 256) cnt[i] = 0;
  __syncthreads();
  const int* dstp = ei + NE;
  int base = blockIdx.x * EPB;
#pragma unroll 4
  for (int k = 0; k < 16; k++) {
    int e = base + k * 256 + tid;
    if (e < NE) atomicAdd(&cnt[dstp[e] >> 9], 1u);
  }
  __syncthreads();
  for (int i = tid; i < NBUK; i += 256) g_pscan[i * NBLK + blockIdx.x] = cnt[i];
}

__global__ __launch_bounds__(1024) void scn_block_kernel() {
  __shared__ uint sd[1024];
  int tid = threadIdx.x;
  int i = blockIdx.x * 1024 + tid;
  uint v = (i < SCN) ? g_pscan[i] : 0;
  sd[tid] = v;
  __syncthreads();
  for (int off = 1; off < 1024; off <<= 1) {
    uint x = (tid >= off) ? sd[tid - off] : 0;
    __syncthreads();
    sd[tid] += x;
    __syncthreads();
  }
  if (i < SCN) g_pscan[i] = sd[tid] - v;  // exclusive within block
  if (tid == 1023) g_bsum2[blockIdx.x] = sd[1023];
}

__global__ void scn_tops_kernel() {  // 1 block, 256 threads
  __shared__ uint sd[256];
  int tid = threadIdx.x;
  uint v = (tid < SCNB) ? g_bsum2[tid] : 0;
  sd[tid] = v;
  __syncthreads();
  for (int off = 1; off < 256; off <<= 1) {
    uint x = (tid >= off) ? sd[tid - off] : 0;
    __syncthreads();
    sd[tid] += x;
    __syncthreads();
  }
  g_bsum2[tid] = sd[tid] - v;  // exclusive scan of block sums
}

__global__ __launch_bounds__(1024) void scn_add_kernel() {
  int i = blockIdx.x * 1024 + threadIdx.x;
  if (i < SCN) g_pscan[i] += g_bsum2[i >> 10];
}

__global__ __launch_bounds__(256) void p1scatter_kernel(const int* __restrict__ ei) {
  __shared__ uint cur[NBUK];
  int tid = threadIdx.x;
  for (int i = tid; i < NBUK; i += 256) cur[i] = g_pscan[i * NBLK + blockIdx.x];
  __syncthreads();
  const int* srcp = ei;
  const int* dstp = ei + NE;
  int base = blockIdx.x * EPB;
#pragma unroll 4
  for (int k = 0; k < 16; k++) {
    int e = base + k * 256 + tid;
    if (e < NE) {
      int d = dstp[e], s = srcp[e];
      uint pos = atomicAdd(&cur[d >> 9], 1u);  // LDS atomic
      g_ebuf[pos] = ((uint)(d & 511) << 17) | (uint)s;
    }
  }
}

__global__ __launch_bounds__(1024) void p2build_kernel() {
  __shared__ uint hist[512];
  __shared__ uint sc[512];
  __shared__ uint cur[512];
  int tid = threadIdx.x;
  int b = blockIdx.x;
  uint bstart = g_pscan[b * NBLK];
  uint bend = (b < NBUK - 1) ? g_pscan[(b + 1) * NBLK] : NE;
  if (tid < 512) hist[tid] = 0;
  __syncthreads();
  for (uint j = bstart + tid; j < bend; j += 1024)
    atomicAdd(&hist[g_ebuf[j] >> 17], 1u);
  __syncthreads();
  uint v = (tid < 512) ? hist[tid] : 0;
  if (tid < 512) sc[tid] = v;
  __syncthreads();
  for (int off = 1; off < 512; off <<= 1) {
    uint x = (tid < 512 && tid >= off) ? sc[tid - off] : 0;
    __syncthreads();
    if (tid < 512) sc[tid] += x;
    __syncthreads();
  }
  if (tid < 512) {
    uint excl = sc[tid] - v;
    cur[tid] = excl;
    int dst = b * 512 + tid;
    if (dst < NN) g_off[dst] = (int)(bstart + excl);
  }
  if (b == NBUK - 1 && tid == 0) g_off[NN] = NE;
  __syncthreads();
  for (uint j = bstart + tid; j < bend; j += 1024) {
    uint val = g_ebuf[j];
    uint pos = bstart + atomicAdd(&cur[val >> 17], 1u);  // LDS atomic
    g_csr[pos] = (int)(val & 0x1FFFFu);
  }
}

// ---------------- W1 -> bf16 transposed pairs ----------------
__global__ __launch_bounds__(256) void w1cast_kernel(const float* __restrict__ W) {
  int idx = blockIdx.x * 256 + threadIdx.x;  // 0..16383
  int n = idx & 63, kp = idx >> 6;           // kp 0..255
  float lo = W[(2 * kp) * HC1 + n];
  float hi = W[(2 * kp + 1) * HC1 + n];
  g_w1bt[n * 256 + kp] = packbf2(lo, hi);
}

// ---------------- GEMM1: g_h1 = X[NN,512] @ W1[512,64] via bf16 MFMA ------------
__device__ __forceinline__ int sw_idx(int row, int g) {
  return row * 32 + ((g ^ (row & 7)) << 2);
}

__global__ __launch_bounds__(256) void gemm1_kernel(const float* __restrict__ X) {
  __shared__ uint sA[64 * 32];
  __shared__ uint sB[64 * 32];
  int t = threadIdx.x;
  int w = t >> 6, l = t & 63;
  int q = l >> 4, c = l & 15;
  int r0 = blockIdx.x * 64;
  int sr = t >> 2;             // 0..63 (row / n)
  int sc = t & 3;              // quarter
  int xrow = r0 + sr; if (xrow >= NN) xrow = NN - 1;
  const float* xbase = &X[(long)xrow * FIN + sc * 16];
  const uint* wbase = &g_w1bt[sr * 256 + sc * 8];
  f32x4 acc[4] = {{0.f,0.f,0.f,0.f},{0.f,0.f,0.f,0.f},{0.f,0.f,0.f,0.f},{0.f,0.f,0.f,0.f}};
  for (int k0 = 0; k0 < FIN; k0 += 64) {
    __syncthreads();
    float4 f0 = *(const float4*)&xbase[k0 + 0];
    float4 f1 = *(const float4*)&xbase[k0 + 4];
    float4 f2 = *(const float4*)&xbase[k0 + 8];
    float4 f3 = *(const float4*)&xbase[k0 + 12];
    uint4 a0 = make_uint4(packbf2(f0.x, f0.y), packbf2(f0.z, f0.w),
                          packbf2(f1.x, f1.y), packbf2(f1.z, f1.w));
    uint4 a1 = make_uint4(packbf2(f2.x, f2.y), packbf2(f2.z, f2.w),
                          packbf2(f3.x, f3.y), packbf2(f3.z, f3.w));
    *(uint4*)&sA[sw_idx(sr, sc * 2 + 0)] = a0;
    *(uint4*)&sA[sw_idx(sr, sc * 2 + 1)] = a1;
    uint4 b0 = *(const uint4*)&wbase[(k0 >> 1) + 0];
    uint4 b1 = *(const uint4*)&wbase[(k0 >> 1) + 4];
    *(uint4*)&sB[sw_idx(sr, sc * 2 + 0)] = b0;
    *(uint4*)&sB[sw_idx(sr, sc * 2 + 1)] = b1;
    __syncthreads();
#pragma unroll
    for (int ks = 0; ks < 2; ks++) {
      int g = ks * 4 + q;
      bf16x8 a = *(const bf16x8*)&sA[sw_idx(w * 16 + c, g)];
#pragma unroll
      for (int nt = 0; nt < 4; nt++) {
        bf16x8 b = *(const bf16x8*)&sB[sw_idx(nt * 16 + c, g)];
        acc[nt] = __builtin_amdgcn_mfma_f32_16x16x32_bf16(a, b, acc[nt], 0, 0, 0);
      }
    }
  }
  int orow0 = r0 + w * 16 + q * 4;
#pragma unroll
  for (int nt = 0; nt < 4; nt++) {
#pragma unroll
    for (int r = 0; r < 4; r++) {
      int row = orow0 + r;
      if (row < NN) g_h1[row * HC1 + nt * 16 + c] = acc[nt][r];
    }
  }
}

// ---------------- attention scores + bf16 packing ----------------
template <int LAYER>
__global__ __launch_bounds__(256) void s_kernel(const float* __restrict__ a_src,
                                                const float* __restrict__ a_dst) {
  constexpr int C = (LAYER == 1) ? C1 : C2;
  const float* Hm = (LAYER == 1) ? g_h1 : g_h2;
  uint* Hb = (LAYER == 1) ? g_h1b : g_h2b;
  int t = blockIdx.x * 256 + threadIdx.x;
  if (t >= NN * NH) return;
  int h = t & 7;
  const float* row = &Hm[t * C];
  float ss = 0.f, sdd = 0.f;
  float vals[C];
#pragma unroll
  for (int c = 0; c < C; c++) {
    float v = row[c];
    vals[c] = v;
    ss = fmaf(v, a_src[h * C + c], ss);
    sdd = fmaf(v, a_dst[h * C + c], sdd);
  }
  g_ssrc[t] = ss;
  g_sdst[t] = sdd;
#pragma unroll
  for (int j = 0; j < C / 2; j++)
    Hb[t * (C / 2) + j] = packbf2(vals[2 * j], vals[2 * j + 1]);
}

// ---------------- layer-1 aggregation (bf16 msgs, 4-edge unroll) ----------------
__global__ __launch_bounds__(256) void agg1_kernel(const float* __restrict__ b1) {
  int gw = (blockIdx.x * 256 + threadIdx.x) >> 6;
  if (gw >= NN) return;
  int lane = threadIdx.x & 63;
  int half = lane >> 5;
  int p = lane & 31;
  int h = p >> 2;
  float sd = g_sdst[gw * NH + h];
  int begin = g_off[gw];
  int cnt = g_off[gw + 1] - begin;
  float acc0 = 0.f, acc1 = 0.f, wsum = 0.f;
  for (int j0 = 0; j0 < cnt; j0 += 64) {
    int m = cnt - j0; if (m > 64) m = 64;
    int srcv = (lane < m) ? g_csr[begin + j0 + lane] : 0;
    int j = 0;
    for (; j + 4 <= m; j += 4) {
      int sa = __shfl(srcv, j + half);
      int sb = __shfl(srcv, j + 2 + half);
      float ta = g_ssrc[sa * NH + h];
      float tb = g_ssrc[sb * NH + h];
      uint va = g_h1b[sa * 32 + p];
      uint vb = g_h1b[sb * 32 + p];
      float ea = __expf(lrelu(ta + sd));
      float eb = __expf(lrelu(tb + sd));
      acc0 = fmaf(blo(va), ea, acc0); acc1 = fmaf(bhi(va), ea, acc1);
      acc0 = fmaf(blo(vb), eb, acc0); acc1 = fmaf(bhi(vb), eb, acc1);
      wsum += ea + eb;
    }
    for (; j + 2 <= m; j += 2) {
      int s = __shfl(srcv, j + half);
      float e = __expf(lrelu(g_ssrc[s * NH + h] + sd));
      uint v = g_h1b[s * 32 + p];
      acc0 = fmaf(blo(v), e, acc0); acc1 = fmaf(bhi(v), e, acc1);
      wsum += e;
    }
    if (j < m) {
      int s = __shfl(srcv, j);
      float e = (half == 0) ? __expf(lrelu(g_ssrc[s * NH + h] + sd)) : 0.f;
      uint v = g_h1b[s * 32 + p];
      acc0 = fmaf(blo(v), e, acc0); acc1 = fmaf(bhi(v), e, acc1);
      wsum += e;
    }
  }
  acc0 += __shfl_xor(acc0, 32);
  acc1 += __shfl_xor(acc1, 32);
  wsum += __shfl_xor(wsum, 32);
  float es = __expf(lrelu(g_ssrc[gw * NH + h] + sd));
  acc0 = fmaf(g_h1[gw * HC1 + 2 * p], es, acc0);
  acc1 = fmaf(g_h1[gw * HC1 + 2 * p + 1], es, acc1);
  wsum += es;
  if (half == 0) {
    float inv = 1.f / wsum;
    float v0 = acc0 * inv + b1[2 * p];
    float v1 = acc1 * inv + b1[2 * p + 1];
    v0 = v0 > 0.f ? v0 : __expf(v0) - 1.f;  // ELU
    v1 = v1 > 0.f ? v1 : __expf(v1) - 1.f;
    *(float2*)&g_hact[gw * HC1 + 2 * p] = make_float2(v0, v1);
  }
}

// ---------------- GEMM2: g_h2 = g_hact[NN,64] @ W2[64,80] ----------------
__global__ __launch_bounds__(256) void gemm2_kernel(const float* __restrict__ W) {
  __shared__ float sW[64 * HC2 + 64];
  int tid = threadIdx.x;
  for (int i = tid; i < 64 * HC2; i += 256) sW[i] = W[i];
  for (int i = 64 * HC2 + tid; i < 64 * HC2 + 64; i += 256) sW[i] = 0.f;
  __syncthreads();
  int lane = tid & 63;
  int w0 = (blockIdx.x * 256 + tid) >> 6;
  for (int r = w0; r < NN; r += 8192) {
    float v = g_hact[r * HC1 + lane];
    float acc0 = 0.f, acc1 = 0.f;
#pragma unroll
    for (int k = 0; k < 64; k++) {
      float xk = __shfl(v, k);
      acc0 = fmaf(xk, sW[k * HC2 + lane], acc0);
      acc1 = fmaf(xk, sW[k * HC2 + 64 + lane], acc1);
    }
    g_h2[r * HC2 + lane] = acc0;
    if (lane < 16) g_h2[r * HC2 + 64 + lane] = acc1;
  }
}

// ------- layer-2 aggregation: softmax + gather + bias + log_softmax, 4x unroll ----
__global__ __launch_bounds__(256) void agg2_kernel(float* __restrict__ out,
                                                   const float* __restrict__ b2) {
  int gw = (blockIdx.x * 256 + threadIdx.x) >> 6;
  if (gw >= NN) return;
  int lane = threadIdx.x & 63;
  int p = lane < 40 ? lane : 39;
  int h = p / 5;
  float sd = g_sdst[gw * NH + h];
  int begin = g_off[gw];
  int cnt = g_off[gw + 1] - begin;
  float acc0 = 0.f, acc1 = 0.f, wsum = 0.f;
  for (int j0 = 0; j0 < cnt; j0 += 64) {
    int m = cnt - j0; if (m > 64) m = 64;
    int srcv = (lane < m) ? g_csr[begin + j0 + lane] : 0;
    int j = 0;
    for (; j + 4 <= m; j += 4) {
      int s0 = __shfl(srcv, j);
      int s1 = __shfl(srcv, j + 1);
      int s2 = __shfl(srcv, j + 2);
      int s3 = __shfl(srcv, j + 3);
      float t0 = g_ssrc[s0 * NH + h];
      float t1 = g_ssrc[s1 * NH + h];
      float t2 = g_ssrc[s2 * NH + h];
      float t3 = g_ssrc[s3 * NH + h];
      uint v0 = g_h2b[s0 * 40 + p];
      uint v1 = g_h2b[s1 * 40 + p];
      uint v2 = g_h2b[s2 * 40 + p];
      uint v3 = g_h2b[s3 * 40 + p];
      float e0 = __expf(lrelu(t0 + sd));
      float e1 = __expf(lrelu(t1 + sd));
      float e2 = __expf(lrelu(t2 + sd));
      float e3 = __expf(lrelu(t3 + sd));
      acc0 = fmaf(blo(v0), e0, acc0); acc1 = fmaf(bhi(v0), e0, acc1);
      acc0 = fmaf(blo(v1), e1, acc0); acc1 = fmaf(bhi(v1), e1, acc1);
      acc0 = fmaf(blo(v2), e2, acc0); acc1 = fmaf(bhi(v2), e2, acc1);
      acc0 = fmaf(blo(v3), e3, acc0); acc1 = fmaf(bhi(v3), e3, acc1);
      wsum += (e0 + e1) + (e2 + e3);
    }
    for (; j < m; j++) {
      int s = __shfl(srcv, j);
      float e = __expf(lrelu(g_ssrc[s * NH + h] + sd));
      uint v = g_h2b[s * 40 + p];
      acc0 = fmaf(blo(v), e, acc0); acc1 = fmaf(bhi(v), e, acc1);
      wsum += e;
    }
  }
  float es = __expf(lrelu(g_ssrc[gw * NH + h] + sd));
  acc0 = fmaf(g_h2[gw * HC2 + 2 * p], es, acc0);
  acc1 = fmaf(g_h2[gw * HC2 + 2 * p + 1], es, acc1);
  wsum += es;
  float inv = 1.f / wsum;
  float v0 = acc0 * inv + b2[2 * p];
  float v1 = acc1 * inv + b2[2 * p + 1];
  float mx = fmaxf(v0, v1);
  for (int o = 32; o; o >>= 1) mx = fmaxf(mx, __shfl_xor(mx, o));
  float spart = (lane < 40) ? __expf(v0 - mx) + __expf(v1 - mx) : 0.f;
  for (int o = 32; o; o >>= 1) spart += __shfl_xor(spart, o);
  float lse = mx + __logf(spart);
  if (lane < 40) *(float2*)&out[gw * HC2 + 2 * p] = make_float2(v0 - lse, v1 - lse);
}

// ---------------- launch ----------------
extern "C" void kernel_launch(void* const* d_in, const int* in_sizes, int n_in,
                              void* d_out, int out_size, void* d_ws, size_t ws_size,
                              hipStream_t stream) {
  (void)in_sizes; (void)n_in; (void)out_size; (void)d_ws; (void)ws_size;
  const float* x   = (const float*)d_in[0];
  const int*   ei  = (const int*)d_in[1];
  const float* W1  = (const float*)d_in[2];
  const float* as1 = (const float*)d_in[3];
  const float* ad1 = (const float*)d_in[4];
  const float* b1  = (const float*)d_in[5];
  const float* W2  = (const float*)d_in[6];
  const float* as2 = (const float*)d_in[7];
  const float* ad2 = (const float*)d_in[8];
  const float* b2  = (const float*)d_in[9];
  float* out = (float*)d_out;

  // CSR build (radix partition, no global atomics; shared by both layers)
  p1count_kernel<<<NBLK, 256, 0, stream>>>(ei);
  scn_block_kernel<<<SCNB, 1024, 0, stream>>>();
  scn_tops_kernel<<<1, 256, 0, stream>>>();
  scn_add_kernel<<<SCNB, 1024, 0, stream>>>();
  p1scatter_kernel<<<NBLK, 256, 0, stream>>>(ei);
  p2build_kernel<<<NBUK, 1024, 0, stream>>>();

  // layer 1
  w1cast_kernel<<<64, 256, 0, stream>>>(W1);
  gemm1_kernel<<<1563, 256, 0, stream>>>(x);
  s_kernel<1><<<3125, 256, 0, stream>>>(as1, ad1);
  agg1_kernel<<<25000, 256, 0, stream>>>(b1);

  // layer 2
  gemm2_kernel<<<2048, 256, 0, stream>>>(W2);
  s_kernel<2><<<3125, 256, 0, stream>>>(as2, ad2);
  agg2_kernel<<<25000, 256, 0, stream>>>(out, b2);
}

// Round 5
// 785.002 us; speedup vs baseline: 1.6821x; 1.0096x over previous
//
#include <hip/hip_runtime.h>
#include <math.h>

#define NN 100000
#define NE 3200000
#define FIN 512
#define NH 8
#define C1 8
#define HC1 64
#define C2 10
#define HC2 80

// radix CSR build
#define EPB 4096
#define NBLK 782           // ceil(NE/EPB)
#define NBUK 196           // ceil(NN/512)
#define SCN (NBUK * NBLK)  // 153272
#define SCNB 150           // ceil(SCN/1024)

typedef unsigned int uint;
typedef unsigned short ushort;
using bf16x8 = __attribute__((ext_vector_type(8))) short;
using f32x4  = __attribute__((ext_vector_type(4))) float;

// ---------------- static scratch ----------------
__device__ float g_h1[NN * HC1];        // x @ W1 (fp32, MFMA out)
__device__ float g_hact[NN * HC1];      // elu(agg1 + b1)
__device__ float g_h2[NN * HC2];        // hact @ W2 (fp32)
__device__ uint  g_h1b[NN * 32];        // h1 as bf16 pairs (ch 2p, 2p+1)
__device__ uint  g_h2b[NN * 40];        // h2 as bf16 pairs
__device__ uint  g_w1bt[64 * 256];      // W1 transposed bf16 pairs: [n][kp]
__device__ float g_ssrc[NN * NH];
__device__ float g_sdst[NN * NH];
__device__ int   g_off[NN + 1];
__device__ uint  g_pscan[SCN];          // per-(bucket,block) counts -> scanned
__device__ uint  g_bsum2[256];
__device__ uint  g_ebuf[NE];            // packed (dlow<<17)|src, bucket-partitioned
__device__ int   g_csr[NE];

__device__ __forceinline__ float lrelu(float x) { return fmaxf(x, 0.2f * x); }

__device__ __forceinline__ uint bf16_rne(float x) {
  uint u = __float_as_uint(x);
  u += 0x7fffu + ((u >> 16) & 1u);
  return u >> 16;
}
__device__ __forceinline__ uint packbf2(float lo, float hi) {
  return bf16_rne(lo) | (bf16_rne(hi) << 16);
}
__device__ __forceinline__ float blo(uint v) { return __uint_as_float(v << 16); }
__device__ __forceinline__ float bhi(uint v) { return __uint_as_float(v & 0xffff0000u); }

// ---------------- CSR build: radix partition by dst, no global atomics ----------
__global__ __launch_bounds__(256) void p1count_kernel(const int* __restrict__ ei) {
  __shared__ uint cnt[NBUK];
  int tid = threadIdx.x;
  for (int i = tid; i < NBUK; i += 256) cnt[i] = 0;
  __syncthreads();
  const int* dstp = ei + NE;
  int base = blockIdx.x * EPB;
#pragma unroll 4
  for (int k = 0; k < 16; k++) {
    int e = base + k * 256 + tid;
    if (e < NE) atomicAdd(&cnt[dstp[e] >> 9], 1u);
  }
  __syncthreads();
  for (int i = tid; i < NBUK; i += 256) g_pscan[i * NBLK + blockIdx.x] = cnt[i];
}

__global__ __launch_bounds__(1024) void scn_block_kernel() {
  __shared__ uint sd[1024];
  int tid = threadIdx.x;
  int i = blockIdx.x * 1024 + tid;
  uint v = (i < SCN) ? g_pscan[i] : 0;
  sd[tid] = v;
  __syncthreads();
  for (int off = 1; off < 1024; off <<= 1) {
    uint x = (tid >= off) ? sd[tid - off] : 0;
    __syncthreads();
    sd[tid] += x;
    __syncthreads();
  }
  if (i < SCN) g_pscan[i] = sd[tid] - v;  // exclusive within block
  if (tid == 1023) g_bsum2[blockIdx.x] = sd[1023];
}

__global__ void scn_tops_kernel() {  // 1 block, 256 threads
  __shared__ uint sd[256];
  int tid = threadIdx.x;
  uint v = (tid < SCNB) ? g_bsum2[tid] : 0;
  sd[tid] = v;
  __syncthreads();
  for (int off = 1; off < 256; off <<= 1) {
    uint x = (tid >= off) ? sd[tid - off] : 0;
    __syncthreads();
    sd[tid] += x;
    __syncthreads();
  }
  g_bsum2[tid] = sd[tid] - v;  // exclusive scan of block sums
}

__global__ __launch_bounds__(1024) void scn_add_kernel() {
  int i = blockIdx.x * 1024 + threadIdx.x;
  if (i < SCN) g_pscan[i] += g_bsum2[i >> 10];
}

__global__ __launch_bounds__(256) void p1scatter_kernel(const int* __restrict__ ei) {
  __shared__ uint cur[NBUK];
  int tid = threadIdx.x;
  for (int i = tid; i < NBUK; i += 256) cur[i] = g_pscan[i * NBLK + blockIdx.x];
  __syncthreads();
  const int* srcp = ei;
  const int* dstp = ei + NE;
  int base = blockIdx.x * EPB;
#pragma unroll 4
  for (int k = 0; k < 16; k++) {
    int e = base + k * 256 + tid;
    if (e < NE) {
      int d = dstp[e], s = srcp[e];
      uint pos = atomicAdd(&cur[d >> 9], 1u);  // LDS atomic
      g_ebuf[pos] = ((uint)(d & 511) << 17) | (uint)s;
    }
  }
}

// Pass 2: per-bucket 4096-bin (dlow x src-range) histogram/scan/scatter.
// Within-node edge lists come out ordered by src>>14 (8 ranges of 16K nodes)
// -> agg kernels sweep src ranges in order => XCD-L2 locality for the gathers.
__global__ __launch_bounds__(1024) void p2build_kernel() {
  __shared__ uint hist[4096];   // reused as cursors in pass 2
  __shared__ uint excl[4096];
  __shared__ uint tsum[1024];
  int tid = threadIdx.x;
  int b = blockIdx.x;
  uint bstart = g_pscan[b * NBLK];
  uint bend = (b < NBUK - 1) ? g_pscan[(b + 1) * NBLK] : NE;
  for (int i = tid; i < 4096; i += 1024) hist[i] = 0;
  __syncthreads();
  for (uint j = bstart + tid; j < bend; j += 1024) {
    uint v = g_ebuf[j];
    uint bin = ((v >> 17) << 3) | ((v & 0x1FFFFu) >> 14);
    atomicAdd(&hist[bin], 1u);
  }
  __syncthreads();
  uint h0 = hist[tid * 4 + 0], h1 = hist[tid * 4 + 1];
  uint h2 = hist[tid * 4 + 2], h3 = hist[tid * 4 + 3];
  uint s1 = h0 + h1, s2 = s1 + h2, s3 = s2 + h3;
  tsum[tid] = s3;
  __syncthreads();
  for (int off = 1; off < 1024; off <<= 1) {
    uint x = (tid >= off) ? tsum[tid - off] : 0;
    __syncthreads();
    tsum[tid] += x;
    __syncthreads();
  }
  uint te = tsum[tid] - s3;  // exclusive over threads
  excl[tid * 4 + 0] = te;
  excl[tid * 4 + 1] = te + h0;
  excl[tid * 4 + 2] = te + s1;
  excl[tid * 4 + 3] = te + s2;
  __syncthreads();
  if (tid < 512) {
    int dst = b * 512 + tid;
    if (dst < NN) g_off[dst] = (int)(bstart + excl[tid * 8]);
  }
  if (b == NBUK - 1 && tid == 0) g_off[NN] = NE;
  for (int i = tid; i < 4096; i += 1024) hist[i] = excl[i];  // cursors
  __syncthreads();
  for (uint j = bstart + tid; j < bend; j += 1024) {
    uint v = g_ebuf[j];
    uint bin = ((v >> 17) << 3) | ((v & 0x1FFFFu) >> 14);
    uint pos = bstart + atomicAdd(&hist[bin], 1u);  // LDS atomic
    g_csr[pos] = (int)(v & 0x1FFFFu);
  }
}

// ---------------- W1 -> bf16 transposed pairs ----------------
__global__ __launch_bounds__(256) void w1cast_kernel(const float* __restrict__ W) {
  int idx = blockIdx.x * 256 + threadIdx.x;  // 0..16383
  int n = idx & 63, kp = idx >> 6;           // kp 0..255
  float lo = W[(2 * kp) * HC1 + n];
  float hi = W[(2 * kp + 1) * HC1 + n];
  g_w1bt[n * 256 + kp] = packbf2(lo, hi);
}

// ---------------- GEMM1: g_h1 = X[NN,512] @ W1[512,64] via bf16 MFMA ------------
__device__ __forceinline__ int sw_idx(int row, int g) {
  return row * 32 + ((g ^ (row & 7)) << 2);
}

__global__ __launch_bounds__(256) void gemm1_kernel(const float* __restrict__ X) {
  __shared__ uint sA[64 * 32];
  __shared__ uint sB[64 * 32];
  int t = threadIdx.x;
  int w = t >> 6, l = t & 63;
  int q = l >> 4, c = l & 15;
  int r0 = blockIdx.x * 64;
  int sr = t >> 2;             // 0..63 (row / n)
  int sc = t & 3;              // quarter
  int xrow = r0 + sr; if (xrow >= NN) xrow = NN - 1;
  const float* xbase = &X[(long)xrow * FIN + sc * 16];
  const uint* wbase = &g_w1bt[sr * 256 + sc * 8];
  f32x4 acc[4] = {{0.f,0.f,0.f,0.f},{0.f,0.f,0.f,0.f},{0.f,0.f,0.f,0.f},{0.f,0.f,0.f,0.f}};
  for (int k0 = 0; k0 < FIN; k0 += 64) {
    __syncthreads();
    float4 f0 = *(const float4*)&xbase[k0 + 0];
    float4 f1 = *(const float4*)&xbase[k0 + 4];
    float4 f2 = *(const float4*)&xbase[k0 + 8];
    float4 f3 = *(const float4*)&xbase[k0 + 12];
    uint4 a0 = make_uint4(packbf2(f0.x, f0.y), packbf2(f0.z, f0.w),
                          packbf2(f1.x, f1.y), packbf2(f1.z, f1.w));
    uint4 a1 = make_uint4(packbf2(f2.x, f2.y), packbf2(f2.z, f2.w),
                          packbf2(f3.x, f3.y), packbf2(f3.z, f3.w));
    *(uint4*)&sA[sw_idx(sr, sc * 2 + 0)] = a0;
    *(uint4*)&sA[sw_idx(sr, sc * 2 + 1)] = a1;
    uint4 b0 = *(const uint4*)&wbase[(k0 >> 1) + 0];
    uint4 b1 = *(const uint4*)&wbase[(k0 >> 1) + 4];
    *(uint4*)&sB[sw_idx(sr, sc * 2 + 0)] = b0;
    *(uint4*)&sB[sw_idx(sr, sc * 2 + 1)] = b1;
    __syncthreads();
#pragma unroll
    for (int ks = 0; ks < 2; ks++) {
      int g = ks * 4 + q;
      bf16x8 a = *(const bf16x8*)&sA[sw_idx(w * 16 + c, g)];
#pragma unroll
      for (int nt = 0; nt < 4; nt++) {
        bf16x8 b = *(const bf16x8*)&sB[sw_idx(nt * 16 + c, g)];
        acc[nt] = __builtin_amdgcn_mfma_f32_16x16x32_bf16(a, b, acc[nt], 0, 0, 0);
      }
    }
  }
  int orow0 = r0 + w * 16 + q * 4;
#pragma unroll
  for (int nt = 0; nt < 4; nt++) {
#pragma unroll
    for (int r = 0; r < 4; r++) {
      int row = orow0 + r;
      if (row < NN) g_h1[row * HC1 + nt * 16 + c] = acc[nt][r];
    }
  }
}

// ---------------- attention scores + bf16 packing ----------------
template <int LAYER>
__global__ __launch_bounds__(256) void s_kernel(const float* __restrict__ a_src,
                                                const float* __restrict__ a_dst) {
  constexpr int C = (LAYER == 1) ? C1 : C2;
  const float* Hm = (LAYER == 1) ? g_h1 : g_h2;
  uint* Hb = (LAYER == 1) ? g_h1b : g_h2b;
  int t = blockIdx.x * 256 + threadIdx.x;
  if (t >= NN * NH) return;
  int h = t & 7;
  const float* row = &Hm[t * C];
  float ss = 0.f, sdd = 0.f;
  float vals[C];
#pragma unroll
  for (int c = 0; c < C; c++) {
    float v = row[c];
    vals[c] = v;
    ss = fmaf(v, a_src[h * C + c], ss);
    sdd = fmaf(v, a_dst[h * C + c], sdd);
  }
  g_ssrc[t] = ss;
  g_sdst[t] = sdd;
#pragma unroll
  for (int j = 0; j < C / 2; j++)
    Hb[t * (C / 2) + j] = packbf2(vals[2 * j], vals[2 * j + 1]);
}

// ---------------- layer-1 aggregation: scalar edge path, 1 channel/lane --------
// Wave per node. Edge index forced into SGPR (readfirstlane) -> addressing on
// SALU; lane = channel (64). Every lane accumulates the full wsum (no reduce).
__global__ __launch_bounds__(256) void agg1_kernel(const float* __restrict__ b1) {
  int gw = __builtin_amdgcn_readfirstlane((int)((blockIdx.x * 256 + threadIdx.x) >> 6));
  if (gw >= NN) return;
  int lane = threadIdx.x & 63;
  int h = lane >> 3;
  const ushort* __restrict__ h1u = (const ushort*)g_h1b;  // bf16 channel view
  float sd = g_sdst[gw * NH + h];
  int begin = g_off[gw];
  int cnt = g_off[gw + 1] - begin;
  float acc = 0.f, wsum = 0.f;
  int j = 0;
  for (; j + 4 <= cnt; j += 4) {
    int s0 = __builtin_amdgcn_readfirstlane(g_csr[begin + j + 0]);
    int s1 = __builtin_amdgcn_readfirstlane(g_csr[begin + j + 1]);
    int s2 = __builtin_amdgcn_readfirstlane(g_csr[begin + j + 2]);
    int s3 = __builtin_amdgcn_readfirstlane(g_csr[begin + j + 3]);
    float t0 = g_ssrc[s0 * NH + h];
    float t1 = g_ssrc[s1 * NH + h];
    float t2 = g_ssrc[s2 * NH + h];
    float t3 = g_ssrc[s3 * NH + h];
    uint v0 = h1u[s0 * HC1 + lane];
    uint v1 = h1u[s1 * HC1 + lane];
    uint v2 = h1u[s2 * HC1 + lane];
    uint v3 = h1u[s3 * HC1 + lane];
    float e0 = __expf(lrelu(t0 + sd));
    float e1 = __expf(lrelu(t1 + sd));
    float e2 = __expf(lrelu(t2 + sd));
    float e3 = __expf(lrelu(t3 + sd));
    acc = fmaf(__uint_as_float(v0 << 16), e0, acc);
    acc = fmaf(__uint_as_float(v1 << 16), e1, acc);
    acc = fmaf(__uint_as_float(v2 << 16), e2, acc);
    acc = fmaf(__uint_as_float(v3 << 16), e3, acc);
    wsum += (e0 + e1) + (e2 + e3);
  }
  for (; j < cnt; j++) {
    int s = __builtin_amdgcn_readfirstlane(g_csr[begin + j]);
    float e = __expf(lrelu(g_ssrc[s * NH + h] + sd));
    acc = fmaf(__uint_as_float((uint)h1u[s * HC1 + lane] << 16), e, acc);
    wsum += e;
  }
  // self loop (fp32)
  float es = __expf(lrelu(g_ssrc[gw * NH + h] + sd));
  acc = fmaf(g_h1[gw * HC1 + lane], es, acc);
  wsum += es;
  float v = acc * (1.f / wsum) + b1[lane];
  g_hact[gw * HC1 + lane] = v > 0.f ? v : __expf(v) - 1.f;  // ELU
}

// ---------------- GEMM2: g_h2 = g_hact[NN,64] @ W2[64,80] ----------------
__global__ __launch_bounds__(256) void gemm2_kernel(const float* __restrict__ W) {
  __shared__ float sW[64 * HC2 + 64];
  int tid = threadIdx.x;
  for (int i = tid; i < 64 * HC2; i += 256) sW[i] = W[i];
  for (int i = 64 * HC2 + tid; i < 64 * HC2 + 64; i += 256) sW[i] = 0.f;
  __syncthreads();
  int lane = tid & 63;
  int w0 = (blockIdx.x * 256 + tid) >> 6;
  for (int r = w0; r < NN; r += 8192) {
    float v = g_hact[r * HC1 + lane];
    float acc0 = 0.f, acc1 = 0.f;
#pragma unroll
    for (int k = 0; k < 64; k++) {
      float xk = __shfl(v, k);
      acc0 = fmaf(xk, sW[k * HC2 + lane], acc0);
      acc1 = fmaf(xk, sW[k * HC2 + 64 + lane], acc1);
    }
    g_h2[r * HC2 + lane] = acc0;
    if (lane < 16) g_h2[r * HC2 + 64 + lane] = acc1;
  }
}

// ------- layer-2 aggregation: scalar edge path + bias + log_softmax ----------
__global__ __launch_bounds__(256) void agg2_kernel(float* __restrict__ out,
                                                   const float* __restrict__ b2) {
  int gw = __builtin_amdgcn_readfirstlane((int)((blockIdx.x * 256 + threadIdx.x) >> 6));
  if (gw >= NN) return;
  int lane = threadIdx.x & 63;
  int p = lane < 40 ? lane : 39;
  int h = p / 5;
  float sd = g_sdst[gw * NH + h];
  int begin = g_off[gw];
  int cnt = g_off[gw + 1] - begin;
  float acc0 = 0.f, acc1 = 0.f, wsum = 0.f;
  int j = 0;
  for (; j + 4 <= cnt; j += 4) {
    int s0 = __builtin_amdgcn_readfirstlane(g_csr[begin + j + 0]);
    int s1 = __builtin_amdgcn_readfirstlane(g_csr[begin + j + 1]);
    int s2 = __builtin_amdgcn_readfirstlane(g_csr[begin + j + 2]);
    int s3 = __builtin_amdgcn_readfirstlane(g_csr[begin + j + 3]);
    float t0 = g_ssrc[s0 * NH + h];
    float t1 = g_ssrc[s1 * NH + h];
    float t2 = g_ssrc[s2 * NH + h];
    float t3 = g_ssrc[s3 * NH + h];
    uint v0 = g_h2b[s0 * 40 + p];
    uint v1 = g_h2b[s1 * 40 + p];
    uint v2 = g_h2b[s2 * 40 + p];
    uint v3 = g_h2b[s3 * 40 + p];
    float e0 = __expf(lrelu(t0 + sd));
    float e1 = __expf(lrelu(t1 + sd));
    float e2 = __expf(lrelu(t2 + sd));
    float e3 = __expf(lrelu(t3 + sd));
    acc0 = fmaf(blo(v0), e0, acc0); acc1 = fmaf(bhi(v0), e0, acc1);
    acc0 = fmaf(blo(v1), e1, acc0); acc1 = fmaf(bhi(v1), e1, acc1);
    acc0 = fmaf(blo(v2), e2, acc0); acc1 = fmaf(bhi(v2), e2, acc1);
    acc0 = fmaf(blo(v3), e3, acc0); acc1 = fmaf(bhi(v3), e3, acc1);
    wsum += (e0 + e1) + (e2 + e3);
  }
  for (; j < cnt; j++) {
    int s = __builtin_amdgcn_readfirstlane(g_csr[begin + j]);
    float e = __expf(lrelu(g_ssrc[s * NH + h] + sd));
    uint v = g_h2b[s * 40 + p];
    acc0 = fmaf(blo(v), e, acc0); acc1 = fmaf(bhi(v), e, acc1);
    wsum += e;
  }
  float es = __expf(lrelu(g_ssrc[gw * NH + h] + sd));
  acc0 = fmaf(g_h2[gw * HC2 + 2 * p], es, acc0);
  acc1 = fmaf(g_h2[gw * HC2 + 2 * p + 1], es, acc1);
  wsum += es;
  float inv = 1.f / wsum;
  float v0 = acc0 * inv + b2[2 * p];
  float v1 = acc1 * inv + b2[2 * p + 1];
  float mx = fmaxf(v0, v1);
  for (int o = 32; o; o >>= 1) mx = fmaxf(mx, __shfl_xor(mx, o));
  float spart = (lane < 40) ? __expf(v0 - mx) + __expf(v1 - mx) : 0.f;
  for (int o = 32; o; o >>= 1) spart += __shfl_xor(spart, o);
  float lse = mx + __logf(spart);
  if (lane < 40) *(float2*)&out[gw * HC2 + 2 * p] = make_float2(v0 - lse, v1 - lse);
}

// ---------------- launch ----------------
extern "C" void kernel_launch(void* const* d_in, const int* in_sizes, int n_in,
                              void* d_out, int out_size, void* d_ws, size_t ws_size,
                              hipStream_t stream) {
  (void)in_sizes; (void)n_in; (void)out_size; (void)d_ws; (void)ws_size;
  const float* x   = (const float*)d_in[0];
  const int*   ei  = (const int*)d_in[1];
  const float* W1  = (const float*)d_in[2];
  const float* as1 = (const float*)d_in[3];
  const float* ad1 = (const float*)d_in[4];
  const float* b1  = (const float*)d_in[5];
  const float* W2  = (const float*)d_in[6];
  const float* as2 = (const float*)d_in[7];
  const float* ad2 = (const float*)d_in[8];
  const float* b2  = (const float*)d_in[9];
  float* out = (float*)d_out;

  // CSR build (radix partition + src-range ordering; shared by both layers)
  p1count_kernel<<<NBLK, 256, 0, stream>>>(ei);
  scn_block_kernel<<<SCNB, 1024, 0, stream>>>();
  scn_tops_kernel<<<1, 256, 0, stream>>>();
  scn_add_kernel<<<SCNB, 1024, 0, stream>>>();
  p1scatter_kernel<<<NBLK, 256, 0, stream>>>(ei);
  p2build_kernel<<<NBUK, 1024, 0, stream>>>();

  // layer 1
  w1cast_kernel<<<64, 256, 0, stream>>>(W1);
  gemm1_kernel<<<1563, 256, 0, stream>>>(x);
  s_kernel<1><<<3125, 256, 0, stream>>>(as1, ad1);
  agg1_kernel<<<25000, 256, 0, stream>>>(b1);

  // layer 2
  gemm2_kernel<<<2048, 256, 0, stream>>>(W2);
  s_kernel<2><<<3125, 256, 0, stream>>>(as2, ad2);
  agg2_kernel<<<25000, 256, 0, stream>>>(out, b2);
}